// Round 3
// baseline (267.608 us; speedup 1.0000x reference)
//
#include <hip/hip_runtime.h>
#include <hip/hip_bf16.h>

// FourierKANLayer: out[n,o] = bias[o] + sum_{i,b} coeffs[o,i,b] * basis[n,i,b]
// basis = [1, sin(m*pi*x) m=1..32, cos(m*pi*x) m=1..32] per (n,i).
//
// R4 = R2's race-free sync skeleton + R3's compiler-opaque compute body.
//  - 4-slot LDS ring (64 KB), stage 2 modes ahead via global_load_lds(16B).
//  - Publish order per mode m: stage(m+2) -> s_waitcnt vmcnt(8) -> s_barrier
//    -> compute(m).  vmcnt BEFORE barrier (each wave certifies its own DMA
//    landed, barrier publishes cross-wave).  vmcnt never drains to 0 in the
//    steady loop (T3/T4).
//  - B-frag reads are inline-asm ds_read_b128 (invisible to the compiler's
//    waitcnt pass => no conservative vmcnt(0) drain before LDS reads), with
//    counted lgkmcnt waits register-tied to the fragments they guard
//    (rule #18: dataflow prevents MFMA hoisting above the wait).
// WAR safety of early stage issue: slot (m+2)&3 was last read at mode m-2;
// every wave's reads retired (lgkmcnt(0) at pair 7) before barrier B_{m-1},
// and stage(m+2) is issued after B_{m-1}.  Race-free.

typedef __bf16 bf16x8 __attribute__((ext_vector_type(8)));
typedef float  f32x4  __attribute__((ext_vector_type(4)));
typedef float  f32x16 __attribute__((ext_vector_type(16)));

#define PI_F 3.14159265358979323846f

// ---------------------------------------------------------------------------
// Repack coeffs [64][64][65] fp32 -> Bp bf16 in 32x32x16 B-fragment order.
// frag = (m*8 + kc)*2 + cc   (m=mode-1 in [0,32), kc in [0,8), cc in [0,2))
// lane: col o = cc*32 + (lane&31), kq = lane>>5
// t in [0,8): i = kc*8 + kq*4 + (t>>1); b = (t&1) ? 33+m : 1+m
// Bp[frag*512 + lane*8 + t] = coeffs[o][i][b]
// bias2[o] = bias[o] + sum_i coeffs[o][i][0]  (block 0, threads 0..63).
// ---------------------------------------------------------------------------
__global__ __launch_bounds__(256) void fkan_repack(
    const float* __restrict__ coeffs, const float* __restrict__ bias,
    __bf16* __restrict__ Bp, float* __restrict__ bias2) {
  int gid  = blockIdx.x * 256 + threadIdx.x;   // 0 .. 32767
  int lane = gid & 63;
  int frag = gid >> 6;                          // 0..511
  int m  = frag >> 4;
  int kc = (frag >> 1) & 7;
  int cc = frag & 1;
  int o  = cc * 32 + (lane & 31);
  int kq = lane >> 5;

  bf16x8 v;
  #pragma unroll
  for (int t = 0; t < 8; ++t) {
    int i = kc * 8 + kq * 4 + (t >> 1);
    int b = (t & 1) ? (33 + m) : (1 + m);
    v[t] = (__bf16)coeffs[(o * 64 + i) * 65 + b];
  }
  *(bf16x8*)(Bp + (size_t)frag * 512 + lane * 8) = v;

  if (blockIdx.x == 0 && threadIdx.x < 64) {
    int oo = threadIdx.x;
    float s = bias[oo];
    #pragma unroll 4
    for (int ii = 0; ii < 64; ++ii) s += coeffs[(oo * 64 + ii) * 65 + 0];
    bias2[oo] = s;
  }
}

// ---------------------------------------------------------------------------
// Staging: each wave DMAs its 4 KB quarter of mode m's 16 KB B-tile.
// ---------------------------------------------------------------------------
__device__ __forceinline__ void stage_slice(const __bf16* __restrict__ Bp,
                                            __bf16* dst, int m, int wave,
                                            int lane) {
  const char* g = (const char*)Bp + (size_t)m * 16384 + wave * 4096 + lane * 16;
  char* l = (char*)dst + wave * 4096;
  #pragma unroll
  for (int r = 0; r < 4; ++r) {
    __builtin_amdgcn_global_load_lds(
        (const __attribute__((address_space(1))) void*)(g + r * 1024),
        (__attribute__((address_space(3))) void*)(l + r * 1024), 16, 0, 0);
  }
}

typedef __attribute__((address_space(3))) const char* lds_ptr_t;

// Inline-asm ds_read_b128: opaque to the compiler's waitcnt pass.
#define DSRD(d, b, OFF) \
  asm volatile("ds_read_b128 %0, %1 offset:" #OFF : "=v"(d) : "v"(b))

// Counted lgkm wait TIED to the two fragment regs it guards (rule #18 safe).
#define LGKMW(N, a, b) \
  asm volatile("s_waitcnt lgkmcnt(" #N ")" : "+v"(a), "+v"(b))

#define ASM_VMCNT(N) asm volatile("s_waitcnt vmcnt(" #N ")")

// ---------------------------------------------------------------------------
// One mode: 16 asm ds_read_b128 (4 pairs issued ahead), counted lgkmcnt,
// 16 MFMA 32x32x16, then Chebyshev advance (sN/cN <- T*sA/cA - sN/cN).
// lgkm counts: at pair kc, issued = min(kc+5,8) pairs; wait for pairs<=kc:
// kc 0..3 -> 8, then 6,4,2,0.  lgkmcnt(0) at pair 7 guarantees all LDS reads
// retired before the wave reaches the next s_barrier (WAR publish).
// ---------------------------------------------------------------------------
__device__ __forceinline__ void mode_compute(lds_ptr_t base,
    const float* sA, const float* cA, float* sN, float* cN,
    const float* T, f32x16* acc) {
  bf16x8 f00, f01, f10, f11, f20, f21, f30, f31;
  bf16x8 f40, f41, f50, f51, f60, f61, f70, f71;

  DSRD(f00, base, 0);     DSRD(f01, base, 1024);
  DSRD(f10, base, 2048);  DSRD(f11, base, 3072);
  DSRD(f20, base, 4096);  DSRD(f21, base, 5120);
  DSRD(f30, base, 6144);  DSRD(f31, base, 7168);

#define AF(kc) bf16x8 af##kc; {                                         \
    af##kc[0] = (__bf16)sA[kc * 4 + 0]; af##kc[1] = (__bf16)cA[kc * 4 + 0]; \
    af##kc[2] = (__bf16)sA[kc * 4 + 1]; af##kc[3] = (__bf16)cA[kc * 4 + 1]; \
    af##kc[4] = (__bf16)sA[kc * 4 + 2]; af##kc[5] = (__bf16)cA[kc * 4 + 2]; \
    af##kc[6] = (__bf16)sA[kc * 4 + 3]; af##kc[7] = (__bf16)cA[kc * 4 + 3]; }
#define MM(kc, fa, fb)                                                        \
    acc[0] = __builtin_amdgcn_mfma_f32_32x32x16_bf16(af##kc, fa, acc[0], 0, 0, 0); \
    acc[1] = __builtin_amdgcn_mfma_f32_32x32x16_bf16(af##kc, fb, acc[1], 0, 0, 0);

  DSRD(f40, base, 8192);  DSRD(f41, base, 9216);
  AF(0); LGKMW(8, f00, f01); MM(0, f00, f01);
  DSRD(f50, base, 10240); DSRD(f51, base, 11264);
  AF(1); LGKMW(8, f10, f11); MM(1, f10, f11);
  DSRD(f60, base, 12288); DSRD(f61, base, 13312);
  AF(2); LGKMW(8, f20, f21); MM(2, f20, f21);
  DSRD(f70, base, 14336); DSRD(f71, base, 15360);
  AF(3); LGKMW(8, f30, f31); MM(3, f30, f31);
  AF(4); LGKMW(6, f40, f41); MM(4, f40, f41);
  AF(5); LGKMW(4, f50, f51); MM(5, f50, f51);
  AF(6); LGKMW(2, f60, f61); MM(6, f60, f61);
  AF(7); LGKMW(0, f70, f71); MM(7, f70, f71);
#undef AF
#undef MM

  // Chebyshev advance (pure VALU; scheduler interleaves into lgkm-wait gaps).
  #pragma unroll
  for (int p = 0; p < 32; ++p) {
    sN[p] = fmaf(T[p], sA[p], -sN[p]);
    cN[p] = fmaf(T[p], cA[p], -cN[p]);
  }
}

// ---------------------------------------------------------------------------
// Main kernel: 256 threads = 4 waves; block = 128 rows x 64 cols; grid = 512.
// Mode m section: stage(m+2) -> vmcnt(8) [stage(m) landed; m+1,m+2 in
// flight] -> s_barrier [publish] -> compute(m).
// ---------------------------------------------------------------------------
__global__ __launch_bounds__(256, 2) void fkan_main(
    const float* __restrict__ x, const __bf16* __restrict__ Bp,
    const float* __restrict__ bias2, float* __restrict__ out) {
  __shared__ __bf16 Bs[4][8192];   // 4 x 16 KB ring buffer (64 KB)

  int tid  = threadIdx.x;
  int wave = tid >> 6;
  int lane = tid & 63;
  int kq   = lane >> 5;
  int cl   = lane & 31;
  int row  = blockIdx.x * 128 + wave * 32 + cl;

  lds_ptr_t base0 = (lds_ptr_t)(&Bs[0][0]) + lane * 16;
  lds_ptr_t base1 = base0 + 16384;
  lds_ptr_t base2 = base0 + 32768;
  lds_ptr_t base3 = base0 + 49152;

  // --- init: sincos(pi*x) for the lane's 32 (row,i) instances -------------
  float T[32], sp[32], cp[32], sc[32], cc_[32];
  const float* xrow = x + (size_t)row * 64 + kq * 4;
  #pragma unroll
  for (int kc = 0; kc < 8; ++kc) {
    f32x4 v = *(const f32x4*)(xrow + kc * 8);
    #pragma unroll
    for (int e = 0; e < 4; ++e) {
      int p = kc * 4 + e;
      float ss, cs;
      __sincosf(PI_F * v[e], &ss, &cs);
      T[p] = 2.0f * cs;          // Chebyshev multiplier
      sc[p] = ss;  cc_[p] = cs;  // current  = mode 1
      sp[p] = 0.f; cp[p] = 1.f;  // previous = mode 0
    }
  }

  f32x16 acc[2];
  #pragma unroll
  for (int c2 = 0; c2 < 2; ++c2)
    #pragma unroll
    for (int r = 0; r < 16; ++r) acc[c2][r] = 0.f;

  // --- prologue: 2-deep prefetch ------------------------------------------
  stage_slice(Bp, &Bs[0][0], 0, wave, lane);
  stage_slice(Bp, &Bs[1][0], 1, wave, lane);

  // --- main loop: modes 0..27, 4 modes / iteration (ring slots 0,1,2,3) ---
  #pragma unroll 1
  for (int mm = 0; mm < 28; mm += 4) {
    stage_slice(Bp, &Bs[2][0], mm + 2, wave, lane);
    ASM_VMCNT(8);                 // stage(mm) landed
    __builtin_amdgcn_s_barrier();
    mode_compute(base0, sc, cc_, sp, cp, T, acc);      // mode mm

    stage_slice(Bp, &Bs[3][0], mm + 3, wave, lane);
    ASM_VMCNT(8);                 // stage(mm+1) landed
    __builtin_amdgcn_s_barrier();
    mode_compute(base1, sp, cp, sc, cc_, T, acc);      // mode mm+1

    stage_slice(Bp, &Bs[0][0], mm + 4, wave, lane);
    ASM_VMCNT(8);                 // stage(mm+2) landed
    __builtin_amdgcn_s_barrier();
    mode_compute(base2, sc, cc_, sp, cp, T, acc);      // mode mm+2

    stage_slice(Bp, &Bs[1][0], mm + 5, wave, lane);
    ASM_VMCNT(8);                 // stage(mm+3) landed
    __builtin_amdgcn_s_barrier();
    mode_compute(base3, sp, cp, sc, cc_, T, acc);      // mode mm+3
  }

  // --- tail: modes 28..31 (stages 30,31 issued; vmcnt shrinks to 0) -------
  stage_slice(Bp, &Bs[2][0], 30, wave, lane);
  ASM_VMCNT(8);                   // stage(28) landed
  __builtin_amdgcn_s_barrier();
  mode_compute(base0, sc, cc_, sp, cp, T, acc);        // mode 28

  stage_slice(Bp, &Bs[3][0], 31, wave, lane);
  ASM_VMCNT(8);                   // stage(29) landed
  __builtin_amdgcn_s_barrier();
  mode_compute(base1, sp, cp, sc, cc_, T, acc);        // mode 29

  ASM_VMCNT(4);                   // stage(30) landed
  __builtin_amdgcn_s_barrier();
  mode_compute(base2, sc, cc_, sp, cp, T, acc);        // mode 30

  ASM_VMCNT(0);                   // stage(31) landed (final drain is free)
  __builtin_amdgcn_s_barrier();
  mode_compute(base3, sp, cp, sc, cc_, T, acc);        // mode 31

  // --- epilogue: C/D layout col=lane&31, row=(r&3)+8*(r>>2)+4*(lane>>5) ---
  float* orow = out + (size_t)(blockIdx.x * 128 + wave * 32) * 64;
  #pragma unroll
  for (int c2 = 0; c2 < 2; ++c2) {
    float b2 = bias2[c2 * 32 + cl];
    #pragma unroll
    for (int r = 0; r < 16; ++r) {
      int ro = (r & 3) + 8 * (r >> 2) + 4 * kq;
      orow[(size_t)ro * 64 + c2 * 32 + cl] = acc[c2][r] + b2;
    }
  }
}

extern "C" void kernel_launch(void* const* d_in, const int* in_sizes, int n_in,
                              void* d_out, int out_size, void* d_ws, size_t ws_size,
                              hipStream_t stream) {
  const float* x      = (const float*)d_in[0];   // [65536, 64]
  const float* coeffs = (const float*)d_in[1];   // [64, 64, 65]
  const float* bias   = (const float*)d_in[2];   // [64]
  float* out = (float*)d_out;

  __bf16* Bp   = (__bf16*)d_ws;                  // 512 KB
  float* bias2 = (float*)((char*)d_ws + 512 * 1024);

  int n_rows = in_sizes[0] / 64;                 // 65536

  fkan_repack<<<128, 256, 0, stream>>>(coeffs, bias, Bp, bias2);
  fkan_main<<<n_rows / 128, 256, 0, stream>>>(x, Bp, bias2, out);
}

// Round 5
// 114.391 us; speedup vs baseline: 2.3394x; 2.3394x over previous
//
#include <hip/hip_runtime.h>
#include <hip/hip_bf16.h>

// FourierKANLayer: out[n,o] = bias[o] + sum_{i,b} coeffs[o,i,b] * basis[n,i,b]
// basis = [1, sin(m*pi*x) m=1..32, cos(m*pi*x) m=1..32] per (n,i).
//
// R6 = R1's verified numerics + sync (scalar (__bf16) packs, stage-then-
// compute, __syncthreads publish, plain HIP ds_reads) with TWO structural
// edits, no new numeric paths:
//  (1) 2 modes per barrier phase (16 phases, 32 KB staged/phase): halves
//      barrier-resync count, gives the scheduler a 32-MFMA window.
//  (2) mode-B Chebyshev advance hoisted ABOVE mode-A's MFMAs (independent
//      ops, identical fmaf sequence) so the VALU advance overlaps the
//      MFMA/LDS stream instead of sitting on the critical path.
// R5 post-mortem: v_cvt_pk_bf16_f32 packing broke numerics (absmax 1.046)
// and is a known perf loss (m240) -- reverted to scalar casts.

typedef __bf16 bf16x8 __attribute__((ext_vector_type(8)));
typedef float  f32x4  __attribute__((ext_vector_type(4)));
typedef float  f32x16 __attribute__((ext_vector_type(16)));

#define PI_F 3.14159265358979323846f

// ---------------------------------------------------------------------------
// Repack coeffs [64][64][65] fp32 -> Bp bf16 in 32x32x16 B-fragment order.
// frag = (m*8 + kc)*2 + cc   (m=mode-1 in [0,32), kc in [0,8), cc in [0,2))
// lane: col o = cc*32 + (lane&31), kq = lane>>5
// t in [0,8): i = kc*8 + kq*4 + (t>>1); b = (t&1) ? 33+m : 1+m
// Bp[frag*512 + lane*8 + t] = coeffs[o][i][b]
// bias2[o] = bias[o] + sum_i coeffs[o][i][0]  (block 0, threads 0..63).
// ---------------------------------------------------------------------------
__global__ __launch_bounds__(256) void fkan_repack(
    const float* __restrict__ coeffs, const float* __restrict__ bias,
    __bf16* __restrict__ Bp, float* __restrict__ bias2) {
  int gid  = blockIdx.x * 256 + threadIdx.x;   // 0 .. 32767
  int lane = gid & 63;
  int frag = gid >> 6;                          // 0..511
  int m  = frag >> 4;
  int kc = (frag >> 1) & 7;
  int cc = frag & 1;
  int o  = cc * 32 + (lane & 31);
  int kq = lane >> 5;

  bf16x8 v;
  #pragma unroll
  for (int t = 0; t < 8; ++t) {
    int i = kc * 8 + kq * 4 + (t >> 1);
    int b = (t & 1) ? (33 + m) : (1 + m);
    v[t] = (__bf16)coeffs[(o * 64 + i) * 65 + b];
  }
  *(bf16x8*)(Bp + (size_t)frag * 512 + lane * 8) = v;

  if (blockIdx.x == 0 && threadIdx.x < 64) {
    int oo = threadIdx.x;
    float s = bias[oo];
    #pragma unroll 4
    for (int ii = 0; ii < 64; ++ii) s += coeffs[(oo * 64 + ii) * 65 + 0];
    bias2[oo] = s;
  }
}

// ---------------------------------------------------------------------------
// Staging: DMA one PHASE (modes 2p, 2p+1; 32 KB contiguous in Bp) into dst.
// Each wave covers its 4 KB quarter of each 16 KB mode-tile (8 loads).
// ---------------------------------------------------------------------------
__device__ __forceinline__ void stage_pair(const __bf16* __restrict__ Bp,
                                           __bf16* dst, int ph, int wave,
                                           int lane) {
  const char* g = (const char*)Bp + (size_t)ph * 32768 + wave * 4096 + lane * 16;
  char* l = (char*)dst + wave * 4096;
  #pragma unroll
  for (int r = 0; r < 4; ++r) {
    __builtin_amdgcn_global_load_lds(
        (const __attribute__((address_space(1))) void*)(g + r * 1024),
        (__attribute__((address_space(3))) void*)(l + r * 1024), 16, 0, 0);
    __builtin_amdgcn_global_load_lds(
        (const __attribute__((address_space(1))) void*)(g + 16384 + r * 1024),
        (__attribute__((address_space(3))) void*)(l + 16384 + r * 1024),
        16, 0, 0);
  }
}

// ---------------------------------------------------------------------------
// One phase = 2 modes from one 32 KB buffer.
// Order: advance(B) first (independent of mode-A MFMAs; takes the VALU off
// the MFMA critical path), then mode-A MFMAs, mode-B MFMAs, advance(A).
// Packing = scalar (__bf16) casts (R1-verified numerics).
// Entering phase p: sA/cA = freq 2p+1, sB/cB = freq 2p.
//   advance(B):  sB <- T*sA - sB  = freq 2p+2
//   mode 2p  (freq 2p+1): A from sA/cA, B-tile at buf
//   mode 2p+1(freq 2p+2): A from sB/cB, B-tile at buf + 8192 elems
//   advance(A):  sA <- T*sB - sA  = freq 2p+3
// ---------------------------------------------------------------------------
__device__ __forceinline__ void phase_compute(const __bf16* buf, int lane,
    const float* T, float* sA, float* cA, float* sB, float* cB,
    f32x16* acc) {
  #pragma unroll
  for (int p = 0; p < 32; ++p) {
    sB[p] = fmaf(T[p], sA[p], -sB[p]);
    cB[p] = fmaf(T[p], cA[p], -cB[p]);
  }
  #pragma unroll
  for (int kc = 0; kc < 8; ++kc) {
    bf16x8 af;
    #pragma unroll
    for (int e = 0; e < 4; ++e) {
      af[2 * e]     = (__bf16)sA[kc * 4 + e];
      af[2 * e + 1] = (__bf16)cA[kc * 4 + e];
    }
    #pragma unroll
    for (int c2 = 0; c2 < 2; ++c2) {
      bf16x8 bfv = *(const bf16x8*)(buf + (kc * 2 + c2) * 512 + lane * 8);
      acc[c2] = __builtin_amdgcn_mfma_f32_32x32x16_bf16(af, bfv, acc[c2],
                                                        0, 0, 0);
    }
  }
  #pragma unroll
  for (int kc = 0; kc < 8; ++kc) {
    bf16x8 af;
    #pragma unroll
    for (int e = 0; e < 4; ++e) {
      af[2 * e]     = (__bf16)sB[kc * 4 + e];
      af[2 * e + 1] = (__bf16)cB[kc * 4 + e];
    }
    #pragma unroll
    for (int c2 = 0; c2 < 2; ++c2) {
      bf16x8 bfv = *(const bf16x8*)(buf + 8192 + (kc * 2 + c2) * 512 + lane * 8);
      acc[c2] = __builtin_amdgcn_mfma_f32_32x32x16_bf16(af, bfv, acc[c2],
                                                        0, 0, 0);
    }
  }
  #pragma unroll
  for (int p = 0; p < 32; ++p) {
    sA[p] = fmaf(T[p], sB[p], -sA[p]);
    cA[p] = fmaf(T[p], cB[p], -cA[p]);
  }
}

// ---------------------------------------------------------------------------
// Main kernel: 256 threads = 4 waves; block = 128 rows x 64 cols; grid = 512.
// 16 phases x 2 modes; per phase: stage(next phase, other buffer) ->
// compute(this phase) -> __syncthreads (stage has the whole ~3000-cycle
// phase to land, so the barrier's vmcnt(0) drain is nearly free).
// LDS = 2 x 32 KB -> 2 blocks/CU (grid-limited to 2 anyway).
// ---------------------------------------------------------------------------
__global__ __launch_bounds__(256, 2) void fkan_main(
    const float* __restrict__ x, const __bf16* __restrict__ Bp,
    const float* __restrict__ bias2, float* __restrict__ out) {
  __shared__ __bf16 Bs[2][16384];   // 2 x 32 KB phase double-buffer

  int tid  = threadIdx.x;
  int wave = tid >> 6;
  int lane = tid & 63;
  int kq   = lane >> 5;
  int cl   = lane & 31;
  int row  = blockIdx.x * 128 + wave * 32 + cl;

  // --- init: sincos(pi*x) for the lane's 32 (row,i) instances -------------
  float T[32], sp[32], cp[32], sc[32], cc_[32];
  const float* xrow = x + (size_t)row * 64 + kq * 4;
  #pragma unroll
  for (int kc = 0; kc < 8; ++kc) {
    f32x4 v = *(const f32x4*)(xrow + kc * 8);
    #pragma unroll
    for (int e = 0; e < 4; ++e) {
      int p = kc * 4 + e;
      float ss, cs;
      __sincosf(PI_F * v[e], &ss, &cs);
      T[p] = 2.0f * cs;          // Chebyshev multiplier
      sc[p] = ss;  cc_[p] = cs;  // current  = freq 1
      sp[p] = 0.f; cp[p] = 1.f;  // previous = freq 0
    }
  }

  f32x16 acc[2];
  #pragma unroll
  for (int c2 = 0; c2 < 2; ++c2)
    #pragma unroll
    for (int r = 0; r < 16; ++r) acc[c2][r] = 0.f;

  // --- prologue: stage phase 0 --------------------------------------------
  stage_pair(Bp, &Bs[0][0], 0, wave, lane);
  __syncthreads();

  // --- main loop: phases 0..13 (two phases per iteration, static buffers) -
  #pragma unroll 1
  for (int ph = 0; ph < 14; ph += 2) {
    stage_pair(Bp, &Bs[1][0], ph + 1, wave, lane);
    phase_compute(&Bs[0][0], lane, T, sc, cc_, sp, cp, acc);
    __syncthreads();

    stage_pair(Bp, &Bs[0][0], ph + 2, wave, lane);
    phase_compute(&Bs[1][0], lane, T, sc, cc_, sp, cp, acc);
    __syncthreads();
  }

  // --- tail: phases 14, 15 -------------------------------------------------
  stage_pair(Bp, &Bs[1][0], 15, wave, lane);
  phase_compute(&Bs[0][0], lane, T, sc, cc_, sp, cp, acc);   // phase 14
  __syncthreads();
  phase_compute(&Bs[1][0], lane, T, sc, cc_, sp, cp, acc);   // phase 15

  // --- epilogue: C/D layout col=lane&31, row=(r&3)+8*(r>>2)+4*(lane>>5) ---
  float* orow = out + (size_t)(blockIdx.x * 128 + wave * 32) * 64;
  #pragma unroll
  for (int c2 = 0; c2 < 2; ++c2) {
    float b2 = bias2[c2 * 32 + cl];
    #pragma unroll
    for (int r = 0; r < 16; ++r) {
      int ro = (r & 3) + 8 * (r >> 2) + 4 * kq;
      orow[(size_t)ro * 64 + c2 * 32 + cl] = acc[c2][r] + b2;
    }
  }
}

extern "C" void kernel_launch(void* const* d_in, const int* in_sizes, int n_in,
                              void* d_out, int out_size, void* d_ws, size_t ws_size,
                              hipStream_t stream) {
  const float* x      = (const float*)d_in[0];   // [65536, 64]
  const float* coeffs = (const float*)d_in[1];   // [64, 64, 65]
  const float* bias   = (const float*)d_in[2];   // [64]
  float* out = (float*)d_out;

  __bf16* Bp   = (__bf16*)d_ws;                  // 512 KB
  float* bias2 = (float*)((char*)d_ws + 512 * 1024);

  int n_rows = in_sizes[0] / 64;                 // 65536

  fkan_repack<<<128, 256, 0, stream>>>(coeffs, bias, Bp, bias2);
  fkan_main<<<n_rows / 128, 256, 0, stream>>>(x, Bp, bias2, out);
}